// Round 7
// baseline (236.330 us; speedup 1.0000x reference)
//
#include <hip/hip_runtime.h>
#include <hip/hip_bf16.h>

constexpr int BATCH = 32768;
constexpr int KDIM  = 128;    // IN_F
constexpr int NDIM  = 2048;   // OUT_F

using f32x4  = __attribute__((ext_vector_type(4))) float;
using bf16x8 = __attribute__((ext_vector_type(8))) short;

// ---------------------------------------------------------------------------
// Fragment order for mfma_f32_16x16x32_bf16 (verified R2/R3):
//   A (MxK): lane l holds m = l&15,  k(j) = 4*(l>>4) + (j&3) + 16*(j>>2)
//   B (KxN): lane l holds n = l&15,  same k(j)
//   D:       lane l holds col = l&15, row = (l>>4)*4 + reg
// 2-term split: z = (x_hi + x_lo) @ W_hi  (absmax ~8e-3 < 2e-2 threshold)
//
// R6 lesson: with dynamic LDS the compiler can't see the 131KB/1-block-per-CU
// occupancy cap; its RA targeted 8 waves/EU -> 64 VGPRs -> scratch spills
// (~33MB working set > aggregate L2) -> +228MB HBM FETCH. Pin the RA with
// amdgpu_waves_per_eu(4,4): budget 128 VGPR at the LDS-forced occupancy.
// ---------------------------------------------------------------------------

__device__ inline void split_bf16(float v, ushort& hi, ushort& lo) {
    __hip_bfloat16 h = __float2bfloat16(v);
    float r = v - __bfloat162float(h);
    __hip_bfloat16 l = __float2bfloat16(r);
    hi = *reinterpret_cast<ushort*>(&h);
    lo = *reinterpret_cast<ushort*>(&l);
}

// W [128][2048] -> Bh[nt=128][kk=4][lane=64][j=8]  (hi only)
__global__ __launch_bounds__(256)
void conv_w_kernel(const float* __restrict__ W, ushort* __restrict__ Bh) {
    int id = blockIdx.x * 256 + threadIdx.x;      // 0 .. 262143
    int j  = id & 7;
    int l  = (id >> 3) & 63;
    int kk = (id >> 9) & 3;
    int nt = id >> 11;
    int k  = kk * 32 + 4 * (l >> 4) + (j & 3) + 16 * (j >> 2);
    int n  = nt * 16 + (l & 15);
    __hip_bfloat16 h = __float2bfloat16(W[k * NDIM + n]);
    Bh[id] = *reinterpret_cast<ushort*>(&h);
}

// x [32768][128] -> A{h,l}[rt=2048][kk=4][lane=64][j=8]
__global__ __launch_bounds__(256)
void conv_x_kernel(const float* __restrict__ x,
                   ushort* __restrict__ Ah, ushort* __restrict__ Al) {
    int id = blockIdx.x * 256 + threadIdx.x;      // 0 .. 4194303
    int j  = id & 7;
    int l  = (id >> 3) & 63;
    int kk = (id >> 9) & 3;
    int rt = id >> 11;
    int k  = kk * 32 + 4 * (l >> 4) + (j & 3) + 16 * (j >> 2);
    int m  = rt * 16 + (l & 15);
    ushort hi, lo;
    split_bf16(x[m * KDIM + k], hi, lo);
    Ah[id] = hi; Al[id] = lo;
}

// ---------------------------------------------------------------------------
// Main: persistent blocks. 1024 thr (16 waves), 16 rows x 2048 cols per tile,
// 8 tiles per block (grid 256, LDS 131 KB forces exactly 1 block/CU = 4
// waves/SIMD). Wave q: GEMM on col-tiles q*8..q*8+7 (acc in AGPRs), then owns
// full row q for sparsemax: coalesced pm/out, wave-local Michelot.
// ---------------------------------------------------------------------------
constexpr int PAD = 2052;                       // %32==4 -> conflict-free
constexpr int LDS_BYTES = 16 * PAD * 4;         // 131328 B
constexpr int GRID = 256;
constexpr int TILES_PER_BLOCK = BATCH / 16 / GRID;   // 8

__global__ void __launch_bounds__(1024)
__attribute__((amdgpu_waves_per_eu(4, 4)))
mfma_sparsemax_kernel(const ushort* __restrict__ Ah, const ushort* __restrict__ Al,
                      const ushort* __restrict__ Bh,
                      const float* __restrict__ pm, float* __restrict__ out) {
    extern __shared__ float zs[];               // [16][PAD]

    const int tid = threadIdx.x;
    const int l   = tid & 63;
    const int q   = tid >> 6;                   // wave id 0..15
    const int g   = l >> 4;

    const bf16x8* A8h = reinterpret_cast<const bf16x8*>(Ah);
    const bf16x8* A8l = reinterpret_cast<const bf16x8*>(Al);
    const bf16x8* B8h = reinterpret_cast<const bf16x8*>(Bh);

    for (int it = 0; it < TILES_PER_BLOCK; ++it) {
        const int rt = blockIdx.x + it * GRID;  // row-tile (16 rows)

        // ---- A fragments for this tile ----
        bf16x8 ah[4], al[4];
        #pragma unroll
        for (int kk = 0; kk < 4; ++kk) {
            ah[kk] = A8h[(rt * 4 + kk) * 64 + l];
            al[kk] = A8l[(rt * 4 + kk) * 64 + l];
        }

        // ---- GEMM: wave q -> col tiles nt = q*8+t ----
        f32x4 acc[8];
        #pragma unroll
        for (int t = 0; t < 8; ++t) {
            const int nt = q * 8 + t;
            bf16x8 b[4];
            #pragma unroll
            for (int kk = 0; kk < 4; ++kk) b[kk] = B8h[(nt * 4 + kk) * 64 + l];
            f32x4 c = {0.f, 0.f, 0.f, 0.f};
            #pragma unroll
            for (int kk = 0; kk < 4; ++kk) {
                c = __builtin_amdgcn_mfma_f32_16x16x32_bf16(ah[kk], b[kk], c, 0, 0, 0);
                c = __builtin_amdgcn_mfma_f32_16x16x32_bf16(al[kk], b[kk], c, 0, 0, 0);
            }
            acc[t] = c;
        }

        // ---- barrier 1: previous iter's zs reads complete ----
        __syncthreads();

        // ---- scatter z into LDS (row-major, padded) ----
        #pragma unroll
        for (int t = 0; t < 8; ++t)
            #pragma unroll
            for (int r = 0; r < 4; ++r)
                zs[(g * 4 + r) * PAD + q * 128 + t * 16 + (l & 15)] = acc[t][r];

        // ---- pm prefetch for my row (hides HBM latency under barrier) ----
        const long grow = (long)rt * 16 + q;
        const f32x4* pmrow = reinterpret_cast<const f32x4*>(pm + grow * NDIM);
        f32x4 pmv[8];
        #pragma unroll
        for (int j = 0; j < 8; ++j) pmv[j] = pmrow[j * 64 + l];

        // ---- barrier 2: zs fully written ----
        __syncthreads();

        // ---- gather my row, gate by pm ----
        const f32x4* zrow = reinterpret_cast<const f32x4*>(zs + q * PAD);
        float zv[32];
        #pragma unroll
        for (int j = 0; j < 8; ++j) {
            f32x4 v = zrow[j * 64 + l];
            zv[j * 4 + 0] = v.x * pmv[j].x;
            zv[j * 4 + 1] = v.y * pmv[j].y;
            zv[j * 4 + 2] = v.z * pmv[j].z;
            zv[j * 4 + 3] = v.w * pmv[j].w;
        }

        // ---- Michelot sparsemax, tau0 = max(rowmax-1, (sum-1)/N) ----
        float s = 0.f, m = zv[0];
        #pragma unroll
        for (int i = 0; i < 32; ++i) { s += zv[i]; m = fmaxf(m, zv[i]); }
        #pragma unroll
        for (int off = 32; off > 0; off >>= 1) {
            s += __shfl_xor(s, off, 64);
            m = fmaxf(m, __shfl_xor(m, off, 64));
        }
        float tau = fmaxf(m - 1.f, (s - 1.f) * (1.f / 2048.f));
        float cprev = -1.f;
        for (int itr = 0; itr < 64; ++itr) {
            float ps = 0.f, pc = 0.f;
            #pragma unroll
            for (int i = 0; i < 32; ++i) {
                bool a = zv[i] > tau;
                ps += a ? zv[i] : 0.f;
                pc += a ? 1.f : 0.f;
            }
            #pragma unroll
            for (int off = 32; off > 0; off >>= 1) {
                ps += __shfl_xor(ps, off, 64);
                pc += __shfl_xor(pc, off, 64);
            }
            tau = (ps - 1.f) / pc;              // pc >= 1 always
            if (pc == cprev) break;             // nested sets + equal count = fixpoint
            cprev = pc;
        }

        // ---- out = max(z - tau, 0), plain coalesced f32x4 stores ----
        f32x4* orow = reinterpret_cast<f32x4*>(out + grow * NDIM);
        #pragma unroll
        for (int j = 0; j < 8; ++j) {
            f32x4 v;
            v.x = fmaxf(zv[j * 4 + 0] - tau, 0.f);
            v.y = fmaxf(zv[j * 4 + 1] - tau, 0.f);
            v.z = fmaxf(zv[j * 4 + 2] - tau, 0.f);
            v.w = fmaxf(zv[j * 4 + 3] - tau, 0.f);
            orow[j * 64 + l] = v;
        }
    }
}

// ---------------------------------------------------------------------------
// Fallback (R1 kernel) if d_ws too small.
// ---------------------------------------------------------------------------
__device__ inline float wave_sum(float v) {
    #pragma unroll
    for (int off = 32; off > 0; off >>= 1) v += __shfl_xor(v, off, 64);
    return v;
}

__global__ __launch_bounds__(256)
void fused_sparsemax_fallback(const float* __restrict__ x,
                              const float* __restrict__ pm,
                              const float* __restrict__ W,
                              float* __restrict__ out) {
    __shared__ float xs[8][KDIM];
    __shared__ float zsf[4][NDIM];
    const int tid  = threadIdx.x;
    const int lane = tid & 63;
    const int wv   = tid >> 6;
    const long r0  = (long)blockIdx.x * 8;
    {
        const float4* src = reinterpret_cast<const float4*>(x + r0 * KDIM);
        reinterpret_cast<float4*>(&xs[0][0])[tid] = src[tid];
    }
    __syncthreads();
    float acc[8][8];
    #pragma unroll
    for (int r = 0; r < 8; ++r)
        #pragma unroll
        for (int j = 0; j < 8; ++j) acc[r][j] = 0.f;
    const float4* Wv4 = reinterpret_cast<const float4*>(W);
    #pragma unroll 4
    for (int k = 0; k < KDIM; ++k) {
        const float4 w0 = Wv4[k * (NDIM / 4) + tid];
        const float4 w1 = Wv4[k * (NDIM / 4) + 256 + tid];
        #pragma unroll
        for (int r = 0; r < 8; ++r) {
            const float xv = xs[r][k];
            acc[r][0] = fmaf(xv, w0.x, acc[r][0]);
            acc[r][1] = fmaf(xv, w0.y, acc[r][1]);
            acc[r][2] = fmaf(xv, w0.z, acc[r][2]);
            acc[r][3] = fmaf(xv, w0.w, acc[r][3]);
            acc[r][4] = fmaf(xv, w1.x, acc[r][4]);
            acc[r][5] = fmaf(xv, w1.y, acc[r][5]);
            acc[r][6] = fmaf(xv, w1.z, acc[r][6]);
            acc[r][7] = fmaf(xv, w1.w, acc[r][7]);
        }
    }
    const float4* pmv = reinterpret_cast<const float4*>(pm);
    #pragma unroll
    for (int half = 0; half < 2; ++half) {
        __syncthreads();
        #pragma unroll
        for (int rr = 0; rr < 4; ++rr) {
            const int r = half * 4 + rr;
            const long rowbase4 = (r0 + r) * (NDIM / 4);
            const float4 m0 = pmv[rowbase4 + tid];
            const float4 m1 = pmv[rowbase4 + 256 + tid];
            float4 z0, z1;
            z0.x = acc[r][0] * m0.x; z0.y = acc[r][1] * m0.y;
            z0.z = acc[r][2] * m0.z; z0.w = acc[r][3] * m0.w;
            z1.x = acc[r][4] * m1.x; z1.y = acc[r][5] * m1.y;
            z1.z = acc[r][6] * m1.z; z1.w = acc[r][7] * m1.w;
            float4* zr = reinterpret_cast<float4*>(&zsf[rr][0]);
            zr[tid] = z0; zr[256 + tid] = z1;
        }
        __syncthreads();
        float zvv[32];
        const float4* zr = reinterpret_cast<const float4*>(&zsf[wv][0]);
        #pragma unroll
        for (int cc = 0; cc < 8; ++cc) {
            const float4 v = zr[cc * 64 + lane];
            zvv[cc * 4 + 0] = v.x; zvv[cc * 4 + 1] = v.y;
            zvv[cc * 4 + 2] = v.z; zvv[cc * 4 + 3] = v.w;
        }
        float s = 0.f;
        #pragma unroll
        for (int i = 0; i < 32; ++i) s += zvv[i];
        s = wave_sum(s);
        float tau = (s - 1.f) / 2048.f;
        float cprev = 2048.f;
        for (int itf = 0; itf < 64; ++itf) {
            float ps = 0.f, pc = 0.f;
            #pragma unroll
            for (int i = 0; i < 32; ++i)
                if (zvv[i] > tau) { ps += zvv[i]; pc += 1.f; }
            ps = wave_sum(ps);
            pc = wave_sum(pc);
            tau = (ps - 1.f) / pc;
            if (pc == cprev) break;
            cprev = pc;
        }
        float4* orow = reinterpret_cast<float4*>(out + (r0 + half * 4 + wv) * NDIM);
        #pragma unroll
        for (int cc = 0; cc < 8; ++cc) {
            float4 v;
            v.x = fmaxf(zvv[cc * 4 + 0] - tau, 0.f);
            v.y = fmaxf(zvv[cc * 4 + 1] - tau, 0.f);
            v.z = fmaxf(zvv[cc * 4 + 2] - tau, 0.f);
            v.w = fmaxf(zvv[cc * 4 + 3] - tau, 0.f);
            orow[cc * 64 + lane] = v;
        }
    }
}

extern "C" void kernel_launch(void* const* d_in, const int* in_sizes, int n_in,
                              void* d_out, int out_size, void* d_ws, size_t ws_size,
                              hipStream_t stream) {
    const float* x  = (const float*)d_in[0];   // [32768, 128]
    const float* pm = (const float*)d_in[1];   // [32768, 2048]
    const float* W  = (const float*)d_in[2];   // [128, 2048]
    float* out = (float*)d_out;

    const size_t szA = (size_t)BATCH * KDIM * sizeof(ushort);   // 8 MB each
    const size_t szB = (size_t)KDIM * NDIM * sizeof(ushort);    // 512 KB
    const size_t need = 2 * szA + szB;

    if (ws_size >= need) {
        char* base = (char*)d_ws;
        ushort* Ah = (ushort*)(base);
        ushort* Al = (ushort*)(base + szA);
        ushort* Bh = (ushort*)(base + 2 * szA);

        conv_x_kernel<<<(BATCH * KDIM) / 256, 256, 0, stream>>>(x, Ah, Al);
        conv_w_kernel<<<(KDIM * NDIM) / 256, 256, 0, stream>>>(W, Bh);
        mfma_sparsemax_kernel<<<GRID, 1024, LDS_BYTES, stream>>>(Ah, Al, Bh, pm, out);
    } else {
        fused_sparsemax_fallback<<<BATCH / 8, 256, 0, stream>>>(x, pm, W, out);
    }
}

// Round 8
// 210.095 us; speedup vs baseline: 1.1249x; 1.1249x over previous
//
#include <hip/hip_runtime.h>
#include <hip/hip_bf16.h>

constexpr int BATCH = 32768;
constexpr int KDIM  = 128;    // IN_F
constexpr int NDIM  = 2048;   // OUT_F

using f32x4  = __attribute__((ext_vector_type(4))) float;
using bf16x8 = __attribute__((ext_vector_type(8))) short;

// ---------------------------------------------------------------------------
// Fragment order for mfma_f32_16x16x32_bf16 (verified R2/R3):
//   A (MxK): lane l holds m = l&15,  k(j) = 4*(l>>4) + (j&3) + 16*(j>>2)
//   B (KxN): lane l holds n = l&15,  same k(j)
//   D:       lane l holds col = l&15, row = (l>>4)*4 + reg
// 2-term split: z = (x_hi + x_lo) @ W_hi  (absmax ~8e-3 < 2e-2 threshold)
//
// R5-R7 lesson: 1024-thr blocks made the RA target 8 waves/EU -> 64 VGPR ->
// scratch spills -> +330MB HBM traffic; attribute knobs didn't override it.
// 512-thr blocks empirically allocate 128 VGPR (R3, clean traffic). Get
// occupancy via 64KB LDS -> 2 blocks/CU, which also overlaps phases across
// blocks instead of serializing one giant block at each barrier.
// ---------------------------------------------------------------------------

__device__ inline void split_bf16(float v, ushort& hi, ushort& lo) {
    __hip_bfloat16 h = __float2bfloat16(v);
    float r = v - __bfloat162float(h);
    __hip_bfloat16 l = __float2bfloat16(r);
    hi = *reinterpret_cast<ushort*>(&h);
    lo = *reinterpret_cast<ushort*>(&l);
}

// W [128][2048] -> Bh[nt=128][kk=4][lane=64][j=8]  (hi only)
__global__ __launch_bounds__(256)
void conv_w_kernel(const float* __restrict__ W, ushort* __restrict__ Bh) {
    int id = blockIdx.x * 256 + threadIdx.x;      // 0 .. 262143
    int j  = id & 7;
    int l  = (id >> 3) & 63;
    int kk = (id >> 9) & 3;
    int nt = id >> 11;
    int k  = kk * 32 + 4 * (l >> 4) + (j & 3) + 16 * (j >> 2);
    int n  = nt * 16 + (l & 15);
    __hip_bfloat16 h = __float2bfloat16(W[k * NDIM + n]);
    Bh[id] = *reinterpret_cast<ushort*>(&h);
}

// x [32768][128] -> A{h,l}[rt=2048][kk=4][lane=64][j=8]
__global__ __launch_bounds__(256)
void conv_x_kernel(const float* __restrict__ x,
                   ushort* __restrict__ Ah, ushort* __restrict__ Al) {
    int id = blockIdx.x * 256 + threadIdx.x;      // 0 .. 4194303
    int j  = id & 7;
    int l  = (id >> 3) & 63;
    int kk = (id >> 9) & 3;
    int rt = id >> 11;
    int k  = kk * 32 + 4 * (l >> 4) + (j & 3) + 16 * (j >> 2);
    int m  = rt * 16 + (l & 15);
    ushort hi, lo;
    split_bf16(x[m * KDIM + k], hi, lo);
    Ah[id] = hi; Al[id] = lo;
}

// ---------------------------------------------------------------------------
// Main: grid 2048, 512 thr (8 waves), 16 rows x 2048 cols per block.
// GEMM: wave q -> col-tiles q*16..q*16+15 (acc[16] f32x4, lives in AGPRs).
// LDS zs[8][2048] = 64 KB (2 blocks/CU). Two 8-row chunks: g-groups 2c,2c+1
// scatter (2-way bank aliasing = free); wave q then owns row c*8+q:
// coalesced pm/out, wave-local Michelot sparsemax (no syncs in iteration).
// ---------------------------------------------------------------------------
constexpr int LDS_BYTES = 8 * NDIM * 4;         // 65536 B
constexpr int GRID = BATCH / 16;                // 2048

__global__ __launch_bounds__(512, 2)
void mfma_sparsemax_kernel(const ushort* __restrict__ Ah, const ushort* __restrict__ Al,
                           const ushort* __restrict__ Bh,
                           const float* __restrict__ pm, float* __restrict__ out) {
    extern __shared__ float zs[];               // [8][2048]

    const int tid = threadIdx.x;
    const int l   = tid & 63;
    const int q   = tid >> 6;                   // wave id 0..7
    const int g   = l >> 4;
    const int rt  = blockIdx.x;                 // row-tile (16 rows)

    const bf16x8* A8h = reinterpret_cast<const bf16x8*>(Ah);
    const bf16x8* A8l = reinterpret_cast<const bf16x8*>(Al);
    const bf16x8* B8h = reinterpret_cast<const bf16x8*>(Bh);

    // ---- A fragments (16 rows) ----
    bf16x8 ah[4], al[4];
    #pragma unroll
    for (int kk = 0; kk < 4; ++kk) {
        ah[kk] = A8h[(rt * 4 + kk) * 64 + l];
        al[kk] = A8l[(rt * 4 + kk) * 64 + l];
    }

    // ---- GEMM: wave q -> col tiles nt = q*16+t, t=0..15 ----
    f32x4 acc[16];
    #pragma unroll
    for (int t = 0; t < 16; ++t) {
        const int nt = q * 16 + t;
        f32x4 c = {0.f, 0.f, 0.f, 0.f};
        #pragma unroll
        for (int kk = 0; kk < 4; ++kk) {
            bf16x8 b = B8h[(nt * 4 + kk) * 64 + l];
            c = __builtin_amdgcn_mfma_f32_16x16x32_bf16(ah[kk], b, c, 0, 0, 0);
            c = __builtin_amdgcn_mfma_f32_16x16x32_bf16(al[kk], b, c, 0, 0, 0);
        }
        acc[t] = c;
    }

    // ---- two 8-row chunks through 64KB LDS ----
    #pragma unroll
    for (int c = 0; c < 2; ++c) {
        __syncthreads();                        // zs free (prev chunk consumed)

        // scatter: lanes whose g-group maps to this chunk (rows g*4+r, g=2c,2c+1)
        if ((g >> 1) == c) {
            const int gr = g & 1;               // 0..1 within chunk
            #pragma unroll
            for (int t = 0; t < 16; ++t)
                #pragma unroll
                for (int r = 0; r < 4; ++r)
                    zs[(gr * 4 + r) * NDIM + q * 256 + t * 16 + (l & 15)] = acc[t][r];
        }

        // pm prefetch for my row (issues under the scatter + barrier)
        const long grow = (long)rt * 16 + c * 8 + q;
        const f32x4* pmrow = reinterpret_cast<const f32x4*>(pm + grow * NDIM);
        f32x4 pmv[8];
        #pragma unroll
        for (int j = 0; j < 8; ++j) pmv[j] = pmrow[j * 64 + l];

        __syncthreads();                        // zs fully written

        // gather my row, gate by pm
        const f32x4* zrow = reinterpret_cast<const f32x4*>(zs + q * NDIM);
        float zv[32];
        #pragma unroll
        for (int j = 0; j < 8; ++j) {
            f32x4 v = zrow[j * 64 + l];
            zv[j * 4 + 0] = v.x * pmv[j].x;
            zv[j * 4 + 1] = v.y * pmv[j].y;
            zv[j * 4 + 2] = v.z * pmv[j].z;
            zv[j * 4 + 3] = v.w * pmv[j].w;
        }

        // Michelot sparsemax, tau0 = max(rowmax-1, (sum-1)/N)
        float s = 0.f, m = zv[0];
        #pragma unroll
        for (int i = 0; i < 32; ++i) { s += zv[i]; m = fmaxf(m, zv[i]); }
        #pragma unroll
        for (int off = 32; off > 0; off >>= 1) {
            s += __shfl_xor(s, off, 64);
            m = fmaxf(m, __shfl_xor(m, off, 64));
        }
        float tau = fmaxf(m - 1.f, (s - 1.f) * (1.f / 2048.f));
        float cprev = -1.f;
        for (int itr = 0; itr < 64; ++itr) {
            float ps = 0.f, pc = 0.f;
            #pragma unroll
            for (int i = 0; i < 32; ++i) {
                bool a = zv[i] > tau;
                ps += a ? zv[i] : 0.f;
                pc += a ? 1.f : 0.f;
            }
            #pragma unroll
            for (int off = 32; off > 0; off >>= 1) {
                ps += __shfl_xor(ps, off, 64);
                pc += __shfl_xor(pc, off, 64);
            }
            tau = (ps - 1.f) / pc;              // pc >= 1 always
            if (pc == cprev) break;             // fixpoint
            cprev = pc;
        }

        // out = max(z - tau, 0), coalesced f32x4
        f32x4* orow = reinterpret_cast<f32x4*>(out + grow * NDIM);
        #pragma unroll
        for (int j = 0; j < 8; ++j) {
            f32x4 v;
            v.x = fmaxf(zv[j * 4 + 0] - tau, 0.f);
            v.y = fmaxf(zv[j * 4 + 1] - tau, 0.f);
            v.z = fmaxf(zv[j * 4 + 2] - tau, 0.f);
            v.w = fmaxf(zv[j * 4 + 3] - tau, 0.f);
            orow[j * 64 + l] = v;
        }
    }
}

// ---------------------------------------------------------------------------
// Fallback (R1 kernel) if d_ws too small.
// ---------------------------------------------------------------------------
__device__ inline float wave_sum(float v) {
    #pragma unroll
    for (int off = 32; off > 0; off >>= 1) v += __shfl_xor(v, off, 64);
    return v;
}

__global__ __launch_bounds__(256)
void fused_sparsemax_fallback(const float* __restrict__ x,
                              const float* __restrict__ pm,
                              const float* __restrict__ W,
                              float* __restrict__ out) {
    __shared__ float xs[8][KDIM];
    __shared__ float zsf[4][NDIM];
    const int tid  = threadIdx.x;
    const int lane = tid & 63;
    const int wv   = tid >> 6;
    const long r0  = (long)blockIdx.x * 8;
    {
        const float4* src = reinterpret_cast<const float4*>(x + r0 * KDIM);
        reinterpret_cast<float4*>(&xs[0][0])[tid] = src[tid];
    }
    __syncthreads();
    float acc[8][8];
    #pragma unroll
    for (int r = 0; r < 8; ++r)
        #pragma unroll
        for (int j = 0; j < 8; ++j) acc[r][j] = 0.f;
    const float4* Wv4 = reinterpret_cast<const float4*>(W);
    #pragma unroll 4
    for (int k = 0; k < KDIM; ++k) {
        const float4 w0 = Wv4[k * (NDIM / 4) + tid];
        const float4 w1 = Wv4[k * (NDIM / 4) + 256 + tid];
        #pragma unroll
        for (int r = 0; r < 8; ++r) {
            const float xv = xs[r][k];
            acc[r][0] = fmaf(xv, w0.x, acc[r][0]);
            acc[r][1] = fmaf(xv, w0.y, acc[r][1]);
            acc[r][2] = fmaf(xv, w0.z, acc[r][2]);
            acc[r][3] = fmaf(xv, w0.w, acc[r][3]);
            acc[r][4] = fmaf(xv, w1.x, acc[r][4]);
            acc[r][5] = fmaf(xv, w1.y, acc[r][5]);
            acc[r][6] = fmaf(xv, w1.z, acc[r][6]);
            acc[r][7] = fmaf(xv, w1.w, acc[r][7]);
        }
    }
    const float4* pmv = reinterpret_cast<const float4*>(pm);
    #pragma unroll
    for (int half = 0; half < 2; ++half) {
        __syncthreads();
        #pragma unroll
        for (int rr = 0; rr < 4; ++rr) {
            const int r = half * 4 + rr;
            const long rowbase4 = (r0 + r) * (NDIM / 4);
            const float4 m0 = pmv[rowbase4 + tid];
            const float4 m1 = pmv[rowbase4 + 256 + tid];
            float4 z0, z1;
            z0.x = acc[r][0] * m0.x; z0.y = acc[r][1] * m0.y;
            z0.z = acc[r][2] * m0.z; z0.w = acc[r][3] * m0.w;
            z1.x = acc[r][4] * m1.x; z1.y = acc[r][5] * m1.y;
            z1.z = acc[r][6] * m1.z; z1.w = acc[r][7] * m1.w;
            float4* zr = reinterpret_cast<float4*>(&zsf[rr][0]);
            zr[tid] = z0; zr[256 + tid] = z1;
        }
        __syncthreads();
        float zvv[32];
        const float4* zr = reinterpret_cast<const float4*>(&zsf[wv][0]);
        #pragma unroll
        for (int cc = 0; cc < 8; ++cc) {
            const float4 v = zr[cc * 64 + lane];
            zvv[cc * 4 + 0] = v.x; zvv[cc * 4 + 1] = v.y;
            zvv[cc * 4 + 2] = v.z; zvv[cc * 4 + 3] = v.w;
        }
        float s = 0.f;
        #pragma unroll
        for (int i = 0; i < 32; ++i) s += zvv[i];
        s = wave_sum(s);
        float tau = (s - 1.f) / 2048.f;
        float cprev = 2048.f;
        for (int itf = 0; itf < 64; ++itf) {
            float ps = 0.f, pc = 0.f;
            #pragma unroll
            for (int i = 0; i < 32; ++i)
                if (zvv[i] > tau) { ps += zvv[i]; pc += 1.f; }
            ps = wave_sum(ps);
            pc = wave_sum(pc);
            tau = (ps - 1.f) / pc;
            if (pc == cprev) break;
            cprev = pc;
        }
        float4* orow = reinterpret_cast<float4*>(out + (r0 + half * 4 + wv) * NDIM);
        #pragma unroll
        for (int cc = 0; cc < 8; ++cc) {
            float4 v;
            v.x = fmaxf(zvv[cc * 4 + 0] - tau, 0.f);
            v.y = fmaxf(zvv[cc * 4 + 1] - tau, 0.f);
            v.z = fmaxf(zvv[cc * 4 + 2] - tau, 0.f);
            v.w = fmaxf(zvv[cc * 4 + 3] - tau, 0.f);
            orow[cc * 64 + lane] = v;
        }
    }
}

extern "C" void kernel_launch(void* const* d_in, const int* in_sizes, int n_in,
                              void* d_out, int out_size, void* d_ws, size_t ws_size,
                              hipStream_t stream) {
    const float* x  = (const float*)d_in[0];   // [32768, 128]
    const float* pm = (const float*)d_in[1];   // [32768, 2048]
    const float* W  = (const float*)d_in[2];   // [128, 2048]
    float* out = (float*)d_out;

    const size_t szA = (size_t)BATCH * KDIM * sizeof(ushort);   // 8 MB each
    const size_t szB = (size_t)KDIM * NDIM * sizeof(ushort);    // 512 KB
    const size_t need = 2 * szA + szB;

    if (ws_size >= need) {
        char* base = (char*)d_ws;
        ushort* Ah = (ushort*)(base);
        ushort* Al = (ushort*)(base + szA);
        ushort* Bh = (ushort*)(base + 2 * szA);

        conv_x_kernel<<<(BATCH * KDIM) / 256, 256, 0, stream>>>(x, Ah, Al);
        conv_w_kernel<<<(KDIM * NDIM) / 256, 256, 0, stream>>>(W, Bh);
        mfma_sparsemax_kernel<<<GRID, 512, LDS_BYTES, stream>>>(Ah, Al, Bh, pm, out);
    } else {
        fused_sparsemax_fallback<<<BATCH / 8, 256, 0, stream>>>(x, pm, W, out);
    }
}